// Round 3
// baseline (311.164 us; speedup 1.0000x reference)
//
#include <hip/hip_runtime.h>
#include <hip/hip_bf16.h>

constexpr int TTOK  = 16384;   // B*S = 8*2048
constexpr int DDIM  = 512;
constexpr int FFDIM = 2048;
constexpr int NEXP  = 8;
constexpr int GB_TOK = 16;             // tokens per gate/scatter block
constexpr int NGB    = TTOK / GB_TOK;  // 1024
constexpr int MAXTILES = TTOK / 128 + NEXP;  // 136: worst-case M-tiles over all experts
constexpr int PREP_GATE = NGB;               // prep blocks [0, NGB) = gate
constexpr int PREP_TR   = 16 * 1024;         // prep blocks [NGB, NGB+16384) = transpose

typedef __attribute__((ext_vector_type(8))) short short8_t;
typedef __attribute__((ext_vector_type(4))) float f32x4_t;

__device__ __forceinline__ unsigned short f2bf(float f) {
    union { float f; unsigned u; } v; v.f = f;
    return (unsigned short)((v.u + 0x7fffu + ((v.u >> 16) & 1u)) >> 16);  // RNE
}

__device__ __forceinline__ void gl_lds16(const void* g, void* l) {
    __builtin_amdgcn_global_load_lds(
        (const __attribute__((address_space(1))) void*)g,
        (__attribute__((address_space(3))) void*)l,
        16, 0, 0);
}

// ---------------- fused prep: gate (blocks [0,1024)) + weight transpose/cast (rest).
// Both proven bodies, merged into one dispatch: removes a launch boundary and lets
// the memory-heavy transpose overlap the compute-heavy gate.
__global__ __launch_bounds__(256) void prep_kernel(const float* __restrict__ x,
                                                   const float* __restrict__ Wg,
                                                   const float* __restrict__ bg,
                                                   int* __restrict__ route,
                                                   float* __restrict__ pmax,
                                                   int* __restrict__ blockCounts,
                                                   const float* __restrict__ W1,
                                                   const float* __restrict__ W2,
                                                   unsigned short* __restrict__ W1T,
                                                   unsigned short* __restrict__ W2T) {
    int tid = threadIdx.x;
    if (blockIdx.x >= PREP_GATE) {
        // ---- transpose + fp32->bf16 cast (R5 32x32 version, measured-good)
        __shared__ float tile[32][33];
        int id = blockIdx.x - PREP_GATE;       // 0 .. 16383
        int z = id >> 10;                      // 0..15
        int t = id & 1023;
        bool isW2 = z >= NEXP;
        int e = isW2 ? z - NEXP : z;
        int R = isW2 ? FFDIM : DDIM;
        int C = isW2 ? DDIM : FFDIM;
        int tilesC = C / 32;
        int c0 = (t % tilesC) * 32;
        int r0 = (t / tilesC) * 32;
        const float* s = (isW2 ? W2 : W1) + (size_t)e * DDIM * FFDIM;
        unsigned short* d = (isW2 ? W2T : W1T) + (size_t)e * DDIM * FFDIM;
        int tx = tid & 31, ty = tid >> 5;      // 32 x 8
        #pragma unroll
        for (int i = 0; i < 4; i++)
            tile[ty + 8 * i][tx] = s[(size_t)(r0 + ty + 8 * i) * C + c0 + tx];
        __syncthreads();
        #pragma unroll
        for (int i = 0; i < 4; i++)
            d[(size_t)(c0 + ty + 8 * i) * R + r0 + tx] = f2bf(tile[tx][ty + 8 * i]);
        return;
    }
    // ---- gating: Wg in registers, f64 accum (R5 version, measured-good)
    __shared__ int cnt[NEXP];
    __shared__ float bgs[NEXP];
    int gb = blockIdx.x;                       // 0 .. 1023
    if (tid < NEXP) { cnt[tid] = 0; bgs[tid] = bg[tid]; }
    __syncthreads();
    int wave = tid >> 6, lane = tid & 63;
    float w[8][8];
    #pragma unroll
    for (int jj = 0; jj < 8; jj++) {
        float4 a = *(const float4*)(Wg + (size_t)(lane * 8 + jj) * NEXP);
        float4 b = *(const float4*)(Wg + (size_t)(lane * 8 + jj) * NEXP + 4);
        w[jj][0] = a.x; w[jj][1] = a.y; w[jj][2] = a.z; w[jj][3] = a.w;
        w[jj][4] = b.x; w[jj][5] = b.y; w[jj][6] = b.z; w[jj][7] = b.w;
    }
    int tbase = gb * GB_TOK + wave * 4;
    for (int it = 0; it < 4; it++) {
        int t = tbase + it;
        float4 xa = *(const float4*)(x + (size_t)t * DDIM + lane * 8);
        float4 xb = *(const float4*)(x + (size_t)t * DDIM + lane * 8 + 4);
        float xs[8] = {xa.x, xa.y, xa.z, xa.w, xb.x, xb.y, xb.z, xb.w};
        double acc[NEXP];
        #pragma unroll
        for (int e = 0; e < NEXP; e++) acc[e] = 0.0;
        #pragma unroll
        for (int jj = 0; jj < 8; jj++) {
            double xv = (double)xs[jj];
            #pragma unroll
            for (int e = 0; e < NEXP; e++) acc[e] += xv * (double)w[jj][e];
        }
        #pragma unroll
        for (int off = 32; off > 0; off >>= 1) {
            #pragma unroll
            for (int e = 0; e < NEXP; e++) acc[e] += __shfl_down(acc[e], off);
        }
        if (lane == 0) {
            double l[NEXP];
            #pragma unroll
            for (int e = 0; e < NEXP; e++) l[e] = acc[e] + (double)bgs[e];
            int r = 0; double lm = l[0];
            #pragma unroll
            for (int e = 1; e < NEXP; e++) if (l[e] > lm) { lm = l[e]; r = e; }
            double s = 0.0;
            #pragma unroll
            for (int e = 0; e < NEXP; e++) s += exp(l[e] - lm);
            route[t] = r;
            pmax[t] = (float)(1.0 / s);
            atomicAdd(&cnt[r], 1);
        }
    }
    __syncthreads();
    if (tid < NEXP) blockCounts[gb * NEXP + tid] = cnt[tid];
}

// ---------------- scan v2: shfl-based, 3 barriers (replaces 20-barrier Hillis-Steele
// on a single CU, which cost ~20 us). Same outputs: stable counting-sort offsets.
__global__ __launch_bounds__(1024) void scan_kernel(const int* __restrict__ blockCounts,
                                                    int* __restrict__ blockOffsets,
                                                    int* __restrict__ segPrefix,
                                                    int* __restrict__ tilePrefix) {
    int b = threadIdx.x, lane = b & 63, wv = b >> 6;   // 16 waves
    int c[NEXP], s[NEXP];
    #pragma unroll
    for (int e = 0; e < NEXP; e++) { c[e] = blockCounts[b * NEXP + e]; s[e] = c[e]; }
    // inclusive scan within each wave (64 lanes)
    #pragma unroll
    for (int off = 1; off < 64; off <<= 1) {
        #pragma unroll
        for (int e = 0; e < NEXP; e++) {
            int t = __shfl_up(s[e], off);
            if (lane >= off) s[e] += t;
        }
    }
    __shared__ int wtot[16][NEXP];
    __shared__ int wpre[16][NEXP];
    __shared__ int base[NEXP + 1];
    if (lane == 63) {
        #pragma unroll
        for (int e = 0; e < NEXP; e++) wtot[wv][e] = s[e];
    }
    __syncthreads();
    if (wv == 0) {
        int t[NEXP];
        #pragma unroll
        for (int e = 0; e < NEXP; e++) t[e] = (lane < 16) ? wtot[lane][e] : 0;
        #pragma unroll
        for (int off = 1; off < 16; off <<= 1) {
            #pragma unroll
            for (int e = 0; e < NEXP; e++) {
                int u = __shfl_up(t[e], off);
                if (lane >= off) t[e] += u;
            }
        }
        if (lane < 16) {
            #pragma unroll
            for (int e = 0; e < NEXP; e++) wpre[lane][e] = t[e] - wtot[lane][e];
        }
        if (lane == 15) {      // t[e] here = grand total for expert e
            int ssum = 0;
            #pragma unroll
            for (int e = 0; e < NEXP; e++) { base[e] = ssum; segPrefix[e] = ssum; ssum += t[e]; }
            base[NEXP] = ssum; segPrefix[NEXP] = ssum;
            int tp = 0; tilePrefix[0] = 0;
            #pragma unroll
            for (int e = 0; e < NEXP; e++) { tp += (t[e] + 127) >> 7; tilePrefix[e + 1] = tp; }
        }
    }
    __syncthreads();
    #pragma unroll
    for (int e = 0; e < NEXP; e++)
        blockOffsets[b * NEXP + e] = base[e] + wpre[wv][e] + s[e] - c[e];
}

// ---------------- scatter: Xs[dst(t)] = bf16(x[t] * pmax[t]), expert-sorted stable order
__global__ __launch_bounds__(256) void scatter_kernel(const float* __restrict__ x,
                                                      const int* __restrict__ route,
                                                      const float* __restrict__ pmax,
                                                      const int* __restrict__ blockOffsets,
                                                      unsigned short* __restrict__ Xs) {
    __shared__ int dstL[GB_TOK];
    __shared__ float pmL[GB_TOK];
    int tid = threadIdx.x;
    int bb = blockIdx.x;
    if (tid < GB_TOK) {
        int t = bb * GB_TOK + tid;
        int r = route[t];
        unsigned long long ltmask = (tid == 0) ? 0ull : ((~0ull) >> (64 - tid));
        int rank = 0;
        #pragma unroll
        for (int e = 0; e < NEXP; e++) {
            unsigned long long m = __ballot(r == e);
            if (r == e) rank = __popcll(m & ltmask);
        }
        dstL[tid] = blockOffsets[bb * NEXP + r] + rank;
        pmL[tid] = pmax[t];
    }
    __syncthreads();
    int wave = tid >> 6, lane = tid & 63;
    for (int rr = 0; rr < 4; rr++) {
        int rowl = wave * 4 + rr;
        int t = bb * GB_TOK + rowl;
        float pm = pmL[rowl];
        const float4* xr = (const float4*)(x + (size_t)t * DDIM) + lane * 2;
        float4 a = xr[0], b = xr[1];
        union { short8_t v; unsigned short s[8]; } o;
        o.s[0] = f2bf(a.x * pm); o.s[1] = f2bf(a.y * pm);
        o.s[2] = f2bf(a.z * pm); o.s[3] = f2bf(a.w * pm);
        o.s[4] = f2bf(b.x * pm); o.s[5] = f2bf(b.y * pm);
        o.s[6] = f2bf(b.z * pm); o.s[7] = f2bf(b.w * pm);
        *(short8_t*)(Xs + (size_t)dstL[rowl] * DDIM + lane * 8) = o.v;
    }
}

// ---------------- segmented GEMM (R0-proven structure: 128x128 tile, BK=64,
// single-buffer 2-barrier loop, 32KB LDS -> 5 blocks/CU cross-block overlap)
// + XCD-chunked m-tile swizzle (proven: FETCH halved) + bf16-epilogue XOR
// de-conflict (write: quads land in 4 distinct 8-bank windows; read: 2-way left).
template <bool RELU, typename OutT, int K, int N>
__global__ __launch_bounds__(256) void gemm_seg(const unsigned short* __restrict__ A,
                                                const unsigned short* __restrict__ Bt,
                                                const float* __restrict__ bias,
                                                OutT* __restrict__ C,
                                                const int* __restrict__ segPrefix,
                                                const int* __restrict__ tilePrefix) {
    int bx = blockIdx.x;
    bx = (bx & 7) * (MAXTILES / 8) + (bx >> 3);   // bijective XCD chunking (136 % 8 == 0)
    int t = bx;
    if (t >= tilePrefix[NEXP]) return;
    int e = 0;
    #pragma unroll
    for (int i = 1; i <= NEXP; i++) e += (t >= tilePrefix[i]) ? 1 : 0;
    int seg1 = segPrefix[e + 1];
    int m0 = segPrefix[e] + (t - tilePrefix[e]) * 128;
    int n0 = blockIdx.y * 128;

    __shared__ unsigned short As[2 * 4096];
    __shared__ unsigned short Bs[2 * 4096];

    int tid = threadIdx.x, wave = tid >> 6, lane = tid & 63;
    const unsigned short* Bte = Bt + (size_t)e * N * K;

    int srow = lane >> 2;
    int sg   = (lane & 3) ^ ((lane >> 2) & 3) ^ ((lane >> 4) & 3);
    int scol = sg * 8;

    f32x4_t acc[4][4];
    #pragma unroll
    for (int i = 0; i < 4; i++)
        #pragma unroll
        for (int j = 0; j < 4; j++) acc[i][j] = (f32x4_t){0.f, 0.f, 0.f, 0.f};

    int wm = (wave & 1) * 64;
    int wn = (wave >> 1) * 64;
    int frow = lane & 15;
    int gr = lane >> 4;
    int fswz = (gr ^ (frow & 3) ^ ((frow >> 2) & 3)) * 8;

    int reg0 = wave * 2;
    int arow0 = m0 + reg0 * 16 + srow;
    arow0 = arow0 < TTOK ? arow0 : TTOK - 1;
    int arow1 = m0 + (reg0 + 1) * 16 + srow;
    arow1 = arow1 < TTOK ? arow1 : TTOK - 1;
    const unsigned short* aptr0 = A + (size_t)arow0 * K + scol;
    const unsigned short* aptr1 = A + (size_t)arow1 * K + scol;
    const unsigned short* bptr0 = Bte + (size_t)(n0 + reg0 * 16 + srow) * K + scol;
    const unsigned short* bptr1 = Bte + (size_t)(n0 + (reg0 + 1) * 16 + srow) * K + scol;

    #pragma unroll
    for (int kc = 0; kc < K; kc += 64) {
        #pragma unroll
        for (int p = 0; p < 2; p++) {
            gl_lds16(aptr0 + kc + p * 32, &As[p * 4096 + reg0 * 512]);
            gl_lds16(aptr1 + kc + p * 32, &As[p * 4096 + (reg0 + 1) * 512]);
            gl_lds16(bptr0 + kc + p * 32, &Bs[p * 4096 + reg0 * 512]);
            gl_lds16(bptr1 + kc + p * 32, &Bs[p * 4096 + (reg0 + 1) * 512]);
        }
        __syncthreads();   // drains vmcnt -> LDS visible
        #pragma unroll
        for (int p = 0; p < 2; p++) {
            short8_t af[4], bfr[4];
            #pragma unroll
            for (int i = 0; i < 4; i++)
                af[i] = *(const short8_t*)&As[p * 4096 + (wm + i * 16 + frow) * 32 + fswz];
            #pragma unroll
            for (int j = 0; j < 4; j++)
                bfr[j] = *(const short8_t*)&Bs[p * 4096 + (wn + j * 16 + frow) * 32 + fswz];
            #pragma unroll
            for (int i = 0; i < 4; i++)
                #pragma unroll
                for (int j = 0; j < 4; j++)
                    acc[i][j] = __builtin_amdgcn_mfma_f32_16x16x32_bf16(af[i], bfr[j], acc[i][j], 0, 0, 0);
        }
        __syncthreads();   // all waves done reading before next overwrite
    }

    int quad = lane >> 4;
    int colb = lane & 15;
    float bv[4];
    #pragma unroll
    for (int j = 0; j < 4; j++) bv[j] = bias[(size_t)e * N + n0 + wn + j * 16 + colb];

    if constexpr (sizeof(OutT) == 2) {
        unsigned short* cbuf = As;   // reuse staging LDS (k-loop fully drained)
        #pragma unroll
        for (int p = 0; p < 2; p++) {
            __syncthreads();
            if ((wave >> 1) == p) {
                #pragma unroll
                for (int i = 0; i < 4; i++)
                    #pragma unroll
                    for (int j = 0; j < 4; j++)
                        #pragma unroll
                        for (int r = 0; r < 4; r++) {
                            float v = acc[i][j][r] + bv[j];
                            if (RELU) v = fmaxf(v, 0.0f);
                            int wrow = wm + i * 16 + quad * 4 + r;
                            // XOR de-conflict: 32B slot flip on row bit 3
                            int cc = (j * 16 + colb) ^ (((wrow >> 3) & 1) * 16);
                            cbuf[wrow * 72 + cc] = f2bf(v);
                        }
            }
            __syncthreads();
            int row = tid >> 1, ch = (tid & 1) * 32;
            int grow = m0 + row;
            if (grow < seg1) {
                #pragma unroll
                for (int k = 0; k < 4; k++) {
                    int vv = (ch + k * 8) ^ (((row >> 3) & 1) * 16);
                    short8_t v = *(const short8_t*)&cbuf[row * 72 + vv];
                    *(short8_t*)&C[(size_t)grow * N + n0 + p * 64 + ch + k * 8] = v;
                }
            }
        }
    } else {
        #pragma unroll
        for (int i = 0; i < 4; i++) {
            #pragma unroll
            for (int j = 0; j < 4; j++) {
                int col = n0 + wn + j * 16 + colb;
                #pragma unroll
                for (int r = 0; r < 4; r++) {
                    int row = m0 + wm + i * 16 + quad * 4 + r;
                    if (row < seg1) {
                        float v = acc[i][j][r] + bv[j];
                        if (RELU) v = fmaxf(v, 0.0f);
                        C[(size_t)row * N + col] = v;
                    }
                }
            }
        }
    }
}

extern "C" void kernel_launch(void* const* d_in, const int* in_sizes, int n_in,
                              void* d_out, int out_size, void* d_ws, size_t ws_size,
                              hipStream_t stream) {
    const float* x  = (const float*)d_in[0];
    const float* Wg = (const float*)d_in[1];
    const float* bg = (const float*)d_in[2];
    const float* W1 = (const float*)d_in[3];
    const float* b1 = (const float*)d_in[4];
    const float* W2 = (const float*)d_in[5];
    const float* b2 = (const float*)d_in[6];
    float* out = (float*)d_out;

    char* ws = (char*)d_ws;
    size_t off = 0;
    auto alloc = [&](size_t bytes) -> char* {
        char* p = ws + off;
        off += (bytes + 255) & ~(size_t)255;
        return p;
    };
    unsigned short* W1T = (unsigned short*)alloc((size_t)NEXP * DDIM * FFDIM * 2);  // [E][FF][D]
    unsigned short* W2T = (unsigned short*)alloc((size_t)NEXP * DDIM * FFDIM * 2);  // [E][D][FF]
    unsigned short* Xs  = (unsigned short*)alloc((size_t)TTOK * DDIM * 2);          // sorted tokens
    unsigned short* H   = (unsigned short*)alloc((size_t)TTOK * FFDIM * 2);         // hidden
    int*   route        = (int*)alloc((size_t)TTOK * 4);
    float* pmaxArr      = (float*)alloc((size_t)TTOK * 4);
    int*   blockCounts  = (int*)alloc((size_t)NGB * NEXP * 4);
    int*   blockOffsets = (int*)alloc((size_t)NGB * NEXP * 4);
    int*   segPrefix    = (int*)alloc((size_t)(NEXP + 1) * 4);
    int*   tilePrefix   = (int*)alloc((size_t)(NEXP + 1) * 4);

    // 1: fused gate + weight transpose/cast (17408 blocks)
    prep_kernel<<<PREP_GATE + PREP_TR, 256, 0, stream>>>(
        x, Wg, bg, route, pmaxArr, blockCounts, W1, W2, W1T, W2T);
    // 2: shfl-based scan -> stable sort offsets + tile list
    scan_kernel<<<1, NGB, 0, stream>>>(blockCounts, blockOffsets, segPrefix, tilePrefix);
    // 3: permute + scale + cast tokens
    scatter_kernel<<<NGB, 256, 0, stream>>>(x, route, pmaxArr, blockOffsets, Xs);
    // 4: H = relu(Xs @ W1[e] + b1[e])  (bf16), 128x128 tiles, grid (136, 16)
    gemm_seg<true, unsigned short, DDIM, FFDIM><<<dim3(MAXTILES, FFDIM / 128, 1), 256, 0, stream>>>(
        Xs, W1T, b1, H, segPrefix, tilePrefix);
    // 5: out = H @ W2[e] + b2[e]  (fp32), 128x128 tiles, grid (136, 4)
    gemm_seg<false, float, FFDIM, DDIM><<<dim3(MAXTILES, DDIM / 128, 1), 256, 0, stream>>>(
        H, W2T, b2, out, segPrefix, tilePrefix);
}

// Round 4
// 294.514 us; speedup vs baseline: 1.0565x; 1.0565x over previous
//
#include <hip/hip_runtime.h>
#include <hip/hip_bf16.h>

constexpr int TTOK  = 16384;   // B*S = 8*2048
constexpr int DDIM  = 512;
constexpr int FFDIM = 2048;
constexpr int NEXP  = 8;
constexpr int GB_TOK = 16;             // tokens per gate/scatter block
constexpr int NGB    = TTOK / GB_TOK;  // 1024
constexpr int MAXTILES = TTOK / 128 + NEXP;  // 136: worst-case M-tiles over all experts
constexpr int TRW1_BLOCKS = 4096;      // 512 tiles/expert * 8 (64x32 tiles)
constexpr int TRW2_XBLK   = 256;       // x-extent of W2-transpose range in gemm1 grid (x16 y = 4096)

typedef __attribute__((ext_vector_type(8))) short short8_t;
typedef __attribute__((ext_vector_type(4))) float f32x4_t;

__device__ __forceinline__ unsigned short f2bf(float f) {
    union { float f; unsigned u; } v; v.f = f;
    return (unsigned short)((v.u + 0x7fffu + ((v.u >> 16) & 1u)) >> 16);  // RNE
}

__device__ __forceinline__ void gl_lds16(const void* g, void* l) {
    __builtin_amdgcn_global_load_lds(
        (const __attribute__((address_space(1))) void*)g,
        (__attribute__((address_space(3))) void*)l,
        16, 0, 0);
}

// ---------------- fast 64(r)x32(c) transpose+cast tile.
// Global: float4 reads (128B segments, 8 lanes/row), short8 writes (128B segments).
// LDS: f32 [64][36] with XOR slot permute p = c ^ (8*((r>>3)&3)):
//  - staging ds_write_b128: 8 lanes/bank-quad (even -> minimum cycles)
//  - readout ds_read_b32: 2-way (free per m136)
// src is [R][C] f32; dst is [C][R] bf16.
__device__ __forceinline__ void tr_tile(const float* __restrict__ src,
                                        unsigned short* __restrict__ dst,
                                        int R, int C, int tileId, float* lds) {
    int tilesC = C / 32;
    int c0 = (tileId % tilesC) * 32;
    int r0 = (tileId / tilesC) * 64;
    int t = threadIdx.x;
    int lr = t >> 3;            // 0..31
    int ls = t & 7;             // float4 slot
    #pragma unroll
    for (int rb = 0; rb < 2; rb++) {
        int row = rb * 32 + lr;
        float4 v = *(const float4*)(src + (size_t)(r0 + row) * C + c0 + 4 * ls);
        int p4 = (4 * ls) ^ (8 * ((row >> 3) & 3));
        *(float4*)(lds + row * 36 + p4) = v;
    }
    __syncthreads();
    int c = t >> 3;             // dst row (= src col) 0..31
    int b = t & 7;              // r-block
    union { short8_t v; unsigned short s[8]; } o;
    #pragma unroll
    for (int j = 0; j < 8; j++) {
        int r = 8 * b + j;
        int p = c ^ (8 * ((r >> 3) & 3));
        o.s[j] = f2bf(lds[r * 36 + p]);
    }
    *(short8_t*)(dst + (size_t)(c0 + c) * R + r0 + 8 * b) = o.v;
}

// ---------------- fused prep: gate (blocks [0,1024)) + W1 transpose/cast (rest)
__global__ __launch_bounds__(256) void prep_kernel(const float* __restrict__ x,
                                                   const float* __restrict__ Wg,
                                                   const float* __restrict__ bg,
                                                   int* __restrict__ route,
                                                   float* __restrict__ pmax,
                                                   int* __restrict__ blockCounts,
                                                   const float* __restrict__ W1,
                                                   unsigned short* __restrict__ W1T) {
    int tid = threadIdx.x;
    if (blockIdx.x >= NGB) {
        __shared__ __align__(16) float tlds[64 * 36];
        int id = blockIdx.x - NGB;             // 0..4095
        int e = id >> 9;                       // 512 tiles per expert
        int tile = id & 511;
        tr_tile(W1 + (size_t)e * DDIM * FFDIM, W1T + (size_t)e * DDIM * FFDIM,
                DDIM, FFDIM, tile, tlds);
        return;
    }
    // ---- gating: Wg in registers, f64 accum (proven)
    __shared__ int cnt[NEXP];
    __shared__ float bgs[NEXP];
    int gb = blockIdx.x;
    if (tid < NEXP) { cnt[tid] = 0; bgs[tid] = bg[tid]; }
    __syncthreads();
    int wave = tid >> 6, lane = tid & 63;
    float w[8][8];
    #pragma unroll
    for (int jj = 0; jj < 8; jj++) {
        float4 a = *(const float4*)(Wg + (size_t)(lane * 8 + jj) * NEXP);
        float4 b = *(const float4*)(Wg + (size_t)(lane * 8 + jj) * NEXP + 4);
        w[jj][0] = a.x; w[jj][1] = a.y; w[jj][2] = a.z; w[jj][3] = a.w;
        w[jj][4] = b.x; w[jj][5] = b.y; w[jj][6] = b.z; w[jj][7] = b.w;
    }
    int tbase = gb * GB_TOK + wave * 4;
    for (int it = 0; it < 4; it++) {
        int t = tbase + it;
        float4 xa = *(const float4*)(x + (size_t)t * DDIM + lane * 8);
        float4 xb = *(const float4*)(x + (size_t)t * DDIM + lane * 8 + 4);
        float xs[8] = {xa.x, xa.y, xa.z, xa.w, xb.x, xb.y, xb.z, xb.w};
        double acc[NEXP];
        #pragma unroll
        for (int e = 0; e < NEXP; e++) acc[e] = 0.0;
        #pragma unroll
        for (int jj = 0; jj < 8; jj++) {
            double xv = (double)xs[jj];
            #pragma unroll
            for (int e = 0; e < NEXP; e++) acc[e] += xv * (double)w[jj][e];
        }
        #pragma unroll
        for (int off = 32; off > 0; off >>= 1) {
            #pragma unroll
            for (int e = 0; e < NEXP; e++) acc[e] += __shfl_down(acc[e], off);
        }
        if (lane == 0) {
            double l[NEXP];
            #pragma unroll
            for (int e = 0; e < NEXP; e++) l[e] = acc[e] + (double)bgs[e];
            int r = 0; double lm = l[0];
            #pragma unroll
            for (int e = 1; e < NEXP; e++) if (l[e] > lm) { lm = l[e]; r = e; }
            double s = 0.0;
            #pragma unroll
            for (int e = 0; e < NEXP; e++) s += exp(l[e] - lm);
            route[t] = r;
            pmax[t] = (float)(1.0 / s);
            atomicAdd(&cnt[r], 1);
        }
    }
    __syncthreads();
    if (tid < NEXP) blockCounts[gb * NEXP + tid] = cnt[tid];
}

// ---------------- scan v2: shfl-based (proven R3)
__global__ __launch_bounds__(1024) void scan_kernel(const int* __restrict__ blockCounts,
                                                    int* __restrict__ blockOffsets,
                                                    int* __restrict__ segPrefix,
                                                    int* __restrict__ tilePrefix) {
    int b = threadIdx.x, lane = b & 63, wv = b >> 6;   // 16 waves
    int c[NEXP], s[NEXP];
    #pragma unroll
    for (int e = 0; e < NEXP; e++) { c[e] = blockCounts[b * NEXP + e]; s[e] = c[e]; }
    #pragma unroll
    for (int off = 1; off < 64; off <<= 1) {
        #pragma unroll
        for (int e = 0; e < NEXP; e++) {
            int t = __shfl_up(s[e], off);
            if (lane >= off) s[e] += t;
        }
    }
    __shared__ int wtot[16][NEXP];
    __shared__ int wpre[16][NEXP];
    __shared__ int base[NEXP + 1];
    if (lane == 63) {
        #pragma unroll
        for (int e = 0; e < NEXP; e++) wtot[wv][e] = s[e];
    }
    __syncthreads();
    if (wv == 0) {
        int t[NEXP];
        #pragma unroll
        for (int e = 0; e < NEXP; e++) t[e] = (lane < 16) ? wtot[lane][e] : 0;
        #pragma unroll
        for (int off = 1; off < 16; off <<= 1) {
            #pragma unroll
            for (int e = 0; e < NEXP; e++) {
                int u = __shfl_up(t[e], off);
                if (lane >= off) t[e] += u;
            }
        }
        if (lane < 16) {
            #pragma unroll
            for (int e = 0; e < NEXP; e++) wpre[lane][e] = t[e] - wtot[lane][e];
        }
        if (lane == 15) {
            int ssum = 0;
            #pragma unroll
            for (int e = 0; e < NEXP; e++) { base[e] = ssum; segPrefix[e] = ssum; ssum += t[e]; }
            base[NEXP] = ssum; segPrefix[NEXP] = ssum;
            int tp = 0; tilePrefix[0] = 0;
            #pragma unroll
            for (int e = 0; e < NEXP; e++) { tp += (t[e] + 127) >> 7; tilePrefix[e + 1] = tp; }
        }
    }
    __syncthreads();
    #pragma unroll
    for (int e = 0; e < NEXP; e++)
        blockOffsets[b * NEXP + e] = base[e] + wpre[wv][e] + s[e] - c[e];
}

// ---------------- scatter (proven)
__global__ __launch_bounds__(256) void scatter_kernel(const float* __restrict__ x,
                                                      const int* __restrict__ route,
                                                      const float* __restrict__ pmax,
                                                      const int* __restrict__ blockOffsets,
                                                      unsigned short* __restrict__ Xs) {
    __shared__ int dstL[GB_TOK];
    __shared__ float pmL[GB_TOK];
    int tid = threadIdx.x;
    int bb = blockIdx.x;
    if (tid < GB_TOK) {
        int t = bb * GB_TOK + tid;
        int r = route[t];
        unsigned long long ltmask = (tid == 0) ? 0ull : ((~0ull) >> (64 - tid));
        int rank = 0;
        #pragma unroll
        for (int e = 0; e < NEXP; e++) {
            unsigned long long m = __ballot(r == e);
            if (r == e) rank = __popcll(m & ltmask);
        }
        dstL[tid] = blockOffsets[bb * NEXP + r] + rank;
        pmL[tid] = pmax[t];
    }
    __syncthreads();
    int wave = tid >> 6, lane = tid & 63;
    for (int rr = 0; rr < 4; rr++) {
        int rowl = wave * 4 + rr;
        int t = bb * GB_TOK + rowl;
        float pm = pmL[rowl];
        const float4* xr = (const float4*)(x + (size_t)t * DDIM) + lane * 2;
        float4 a = xr[0], b = xr[1];
        union { short8_t v; unsigned short s[8]; } o;
        o.s[0] = f2bf(a.x * pm); o.s[1] = f2bf(a.y * pm);
        o.s[2] = f2bf(a.z * pm); o.s[3] = f2bf(a.w * pm);
        o.s[4] = f2bf(b.x * pm); o.s[5] = f2bf(b.y * pm);
        o.s[6] = f2bf(b.z * pm); o.s[7] = f2bf(b.w * pm);
        *(short8_t*)(Xs + (size_t)dstL[rowl] * DDIM + lane * 8) = o.v;
    }
}

// ============================================================================
// GEMM1 fused: proven 128x128/BK=64 2-barrier structure (x<MAXTILES) + W2
// transpose blocks (x in [MAXTILES, MAXTILES+256), id = (x-136)*16 + y -> 4096
// tiles), sharing one 32 KB SMEM region so occupancy is unchanged. The W2
// transpose (~25 us standalone) hides under GEMM1's compute (GEMM1 at only
// 1.6/6.3 TB/s has BW headroom). bf16 out + ReLU + bias, LDS epilogue.
// ============================================================================
__global__ __launch_bounds__(256) void gemm1_fused(const unsigned short* __restrict__ A,
                                                   const unsigned short* __restrict__ Bt,
                                                   const float* __restrict__ bias,
                                                   unsigned short* __restrict__ C,
                                                   const int* __restrict__ segPrefix,
                                                   const int* __restrict__ tilePrefix,
                                                   const float* __restrict__ W2,
                                                   unsigned short* __restrict__ W2T) {
    constexpr int K = DDIM, N = FFDIM;
    __shared__ __align__(16) unsigned short SMEM[16384];   // 32 KB shared by both roles

    if (blockIdx.x >= MAXTILES) {
        int id = (blockIdx.x - MAXTILES) * 16 + blockIdx.y;  // 0..4095
        int e = id >> 9;
        int tile = id & 511;
        tr_tile(W2 + (size_t)e * DDIM * FFDIM, W2T + (size_t)e * DDIM * FFDIM,
                FFDIM, DDIM, tile, (float*)SMEM);
        return;
    }

    int bx = blockIdx.x;
    bx = (bx & 7) * (MAXTILES / 8) + (bx >> 3);   // bijective XCD chunking (136 % 8 == 0)
    int t = bx;
    if (t >= tilePrefix[NEXP]) return;
    int e = 0;
    #pragma unroll
    for (int i = 1; i <= NEXP; i++) e += (t >= tilePrefix[i]) ? 1 : 0;
    int seg1 = segPrefix[e + 1];
    int m0 = segPrefix[e] + (t - tilePrefix[e]) * 128;
    int n0 = blockIdx.y * 128;

    unsigned short* As = SMEM;
    unsigned short* Bs = SMEM + 8192;

    int tid = threadIdx.x, wave = tid >> 6, lane = tid & 63;
    const unsigned short* Bte = Bt + (size_t)e * N * K;

    int srow = lane >> 2;
    int sg   = (lane & 3) ^ ((lane >> 2) & 3) ^ ((lane >> 4) & 3);
    int scol = sg * 8;

    f32x4_t acc[4][4];
    #pragma unroll
    for (int i = 0; i < 4; i++)
        #pragma unroll
        for (int j = 0; j < 4; j++) acc[i][j] = (f32x4_t){0.f, 0.f, 0.f, 0.f};

    int wm = (wave & 1) * 64;
    int wn = (wave >> 1) * 64;
    int frow = lane & 15;
    int gr = lane >> 4;
    int fswz = (gr ^ (frow & 3) ^ ((frow >> 2) & 3)) * 8;

    int reg0 = wave * 2;
    int arow0 = m0 + reg0 * 16 + srow;
    arow0 = arow0 < TTOK ? arow0 : TTOK - 1;
    int arow1 = m0 + (reg0 + 1) * 16 + srow;
    arow1 = arow1 < TTOK ? arow1 : TTOK - 1;
    const unsigned short* aptr0 = A + (size_t)arow0 * K + scol;
    const unsigned short* aptr1 = A + (size_t)arow1 * K + scol;
    const unsigned short* bptr0 = Bte + (size_t)(n0 + reg0 * 16 + srow) * K + scol;
    const unsigned short* bptr1 = Bte + (size_t)(n0 + (reg0 + 1) * 16 + srow) * K + scol;

    #pragma unroll
    for (int kc = 0; kc < K; kc += 64) {
        #pragma unroll
        for (int p = 0; p < 2; p++) {
            gl_lds16(aptr0 + kc + p * 32, &As[p * 4096 + reg0 * 512]);
            gl_lds16(aptr1 + kc + p * 32, &As[p * 4096 + (reg0 + 1) * 512]);
            gl_lds16(bptr0 + kc + p * 32, &Bs[p * 4096 + reg0 * 512]);
            gl_lds16(bptr1 + kc + p * 32, &Bs[p * 4096 + (reg0 + 1) * 512]);
        }
        __syncthreads();
        #pragma unroll
        for (int p = 0; p < 2; p++) {
            short8_t af[4], bfr[4];
            #pragma unroll
            for (int i = 0; i < 4; i++)
                af[i] = *(const short8_t*)&As[p * 4096 + (wm + i * 16 + frow) * 32 + fswz];
            #pragma unroll
            for (int j = 0; j < 4; j++)
                bfr[j] = *(const short8_t*)&Bs[p * 4096 + (wn + j * 16 + frow) * 32 + fswz];
            #pragma unroll
            for (int i = 0; i < 4; i++)
                #pragma unroll
                for (int j = 0; j < 4; j++)
                    acc[i][j] = __builtin_amdgcn_mfma_f32_16x16x32_bf16(af[i], bfr[j], acc[i][j], 0, 0, 0);
        }
        __syncthreads();
    }

    int quad = lane >> 4;
    int colb = lane & 15;
    float bv[4];
    #pragma unroll
    for (int j = 0; j < 4; j++) bv[j] = bias[(size_t)e * N + n0 + wn + j * 16 + colb];

    unsigned short* cbuf = As;
    #pragma unroll
    for (int p = 0; p < 2; p++) {
        __syncthreads();
        if ((wave >> 1) == p) {
            #pragma unroll
            for (int i = 0; i < 4; i++)
                #pragma unroll
                for (int j = 0; j < 4; j++)
                    #pragma unroll
                    for (int r = 0; r < 4; r++) {
                        float v = acc[i][j][r] + bv[j];
                        v = fmaxf(v, 0.0f);
                        int wrow = wm + i * 16 + quad * 4 + r;
                        int cc = (j * 16 + colb) ^ (((wrow >> 3) & 1) * 16);
                        cbuf[wrow * 72 + cc] = f2bf(v);
                    }
        }
        __syncthreads();
        int row = tid >> 1, ch = (tid & 1) * 32;
        int grow = m0 + row;
        if (grow < seg1) {
            #pragma unroll
            for (int k = 0; k < 4; k++) {
                int vv = (ch + k * 8) ^ (((row >> 3) & 1) * 16);
                short8_t v = *(const short8_t*)&cbuf[row * 72 + vv];
                *(short8_t*)&C[(size_t)grow * N + n0 + p * 64 + ch + k * 8] = v;
            }
        }
    }
}

// ---------------- GEMM2 (proven): 128x128, fp32 out + XCD swizzle
template <bool RELU, typename OutT, int K, int N>
__global__ __launch_bounds__(256) void gemm_seg(const unsigned short* __restrict__ A,
                                                const unsigned short* __restrict__ Bt,
                                                const float* __restrict__ bias,
                                                OutT* __restrict__ C,
                                                const int* __restrict__ segPrefix,
                                                const int* __restrict__ tilePrefix) {
    int bx = blockIdx.x;
    bx = (bx & 7) * (MAXTILES / 8) + (bx >> 3);
    int t = bx;
    if (t >= tilePrefix[NEXP]) return;
    int e = 0;
    #pragma unroll
    for (int i = 1; i <= NEXP; i++) e += (t >= tilePrefix[i]) ? 1 : 0;
    int seg1 = segPrefix[e + 1];
    int m0 = segPrefix[e] + (t - tilePrefix[e]) * 128;
    int n0 = blockIdx.y * 128;

    __shared__ unsigned short As[2 * 4096];
    __shared__ unsigned short Bs[2 * 4096];

    int tid = threadIdx.x, wave = tid >> 6, lane = tid & 63;
    const unsigned short* Bte = Bt + (size_t)e * N * K;

    int srow = lane >> 2;
    int sg   = (lane & 3) ^ ((lane >> 2) & 3) ^ ((lane >> 4) & 3);
    int scol = sg * 8;

    f32x4_t acc[4][4];
    #pragma unroll
    for (int i = 0; i < 4; i++)
        #pragma unroll
        for (int j = 0; j < 4; j++) acc[i][j] = (f32x4_t){0.f, 0.f, 0.f, 0.f};

    int wm = (wave & 1) * 64;
    int wn = (wave >> 1) * 64;
    int frow = lane & 15;
    int gr = lane >> 4;
    int fswz = (gr ^ (frow & 3) ^ ((frow >> 2) & 3)) * 8;

    int reg0 = wave * 2;
    int arow0 = m0 + reg0 * 16 + srow;
    arow0 = arow0 < TTOK ? arow0 : TTOK - 1;
    int arow1 = m0 + (reg0 + 1) * 16 + srow;
    arow1 = arow1 < TTOK ? arow1 : TTOK - 1;
    const unsigned short* aptr0 = A + (size_t)arow0 * K + scol;
    const unsigned short* aptr1 = A + (size_t)arow1 * K + scol;
    const unsigned short* bptr0 = Bte + (size_t)(n0 + reg0 * 16 + srow) * K + scol;
    const unsigned short* bptr1 = Bte + (size_t)(n0 + (reg0 + 1) * 16 + srow) * K + scol;

    #pragma unroll
    for (int kc = 0; kc < K; kc += 64) {
        #pragma unroll
        for (int p = 0; p < 2; p++) {
            gl_lds16(aptr0 + kc + p * 32, &As[p * 4096 + reg0 * 512]);
            gl_lds16(aptr1 + kc + p * 32, &As[p * 4096 + (reg0 + 1) * 512]);
            gl_lds16(bptr0 + kc + p * 32, &Bs[p * 4096 + reg0 * 512]);
            gl_lds16(bptr1 + kc + p * 32, &Bs[p * 4096 + (reg0 + 1) * 512]);
        }
        __syncthreads();
        #pragma unroll
        for (int p = 0; p < 2; p++) {
            short8_t af[4], bfr[4];
            #pragma unroll
            for (int i = 0; i < 4; i++)
                af[i] = *(const short8_t*)&As[p * 4096 + (wm + i * 16 + frow) * 32 + fswz];
            #pragma unroll
            for (int j = 0; j < 4; j++)
                bfr[j] = *(const short8_t*)&Bs[p * 4096 + (wn + j * 16 + frow) * 32 + fswz];
            #pragma unroll
            for (int i = 0; i < 4; i++)
                #pragma unroll
                for (int j = 0; j < 4; j++)
                    acc[i][j] = __builtin_amdgcn_mfma_f32_16x16x32_bf16(af[i], bfr[j], acc[i][j], 0, 0, 0);
        }
        __syncthreads();
    }

    int quad = lane >> 4;
    int colb = lane & 15;
    float bv[4];
    #pragma unroll
    for (int j = 0; j < 4; j++) bv[j] = bias[(size_t)e * N + n0 + wn + j * 16 + colb];

    #pragma unroll
    for (int i = 0; i < 4; i++) {
        #pragma unroll
        for (int j = 0; j < 4; j++) {
            int col = n0 + wn + j * 16 + colb;
            #pragma unroll
            for (int r = 0; r < 4; r++) {
                int row = m0 + wm + i * 16 + quad * 4 + r;
                if (row < seg1) {
                    float v = acc[i][j][r] + bv[j];
                    if (RELU) v = fmaxf(v, 0.0f);
                    C[(size_t)row * N + col] = v;
                }
            }
        }
    }
}

extern "C" void kernel_launch(void* const* d_in, const int* in_sizes, int n_in,
                              void* d_out, int out_size, void* d_ws, size_t ws_size,
                              hipStream_t stream) {
    const float* x  = (const float*)d_in[0];
    const float* Wg = (const float*)d_in[1];
    const float* bg = (const float*)d_in[2];
    const float* W1 = (const float*)d_in[3];
    const float* b1 = (const float*)d_in[4];
    const float* W2 = (const float*)d_in[5];
    const float* b2 = (const float*)d_in[6];
    float* out = (float*)d_out;

    char* ws = (char*)d_ws;
    size_t off = 0;
    auto alloc = [&](size_t bytes) -> char* {
        char* p = ws + off;
        off += (bytes + 255) & ~(size_t)255;
        return p;
    };
    unsigned short* W1T = (unsigned short*)alloc((size_t)NEXP * DDIM * FFDIM * 2);  // [E][FF][D]
    unsigned short* W2T = (unsigned short*)alloc((size_t)NEXP * DDIM * FFDIM * 2);  // [E][D][FF]
    unsigned short* Xs  = (unsigned short*)alloc((size_t)TTOK * DDIM * 2);          // sorted tokens
    unsigned short* H   = (unsigned short*)alloc((size_t)TTOK * FFDIM * 2);         // hidden
    int*   route        = (int*)alloc((size_t)TTOK * 4);
    float* pmaxArr      = (float*)alloc((size_t)TTOK * 4);
    int*   blockCounts  = (int*)alloc((size_t)NGB * NEXP * 4);
    int*   blockOffsets = (int*)alloc((size_t)NGB * NEXP * 4);
    int*   segPrefix    = (int*)alloc((size_t)(NEXP + 1) * 4);
    int*   tilePrefix   = (int*)alloc((size_t)(NEXP + 1) * 4);

    // 1: fused gate + fast W1-transpose (5120 blocks)
    prep_kernel<<<NGB + TRW1_BLOCKS, 256, 0, stream>>>(
        x, Wg, bg, route, pmaxArr, blockCounts, W1, W1T);
    // 2: shfl-based scan -> stable sort offsets + tile list
    scan_kernel<<<1, NGB, 0, stream>>>(blockCounts, blockOffsets, segPrefix, tilePrefix);
    // 3: permute + scale + cast tokens
    scatter_kernel<<<NGB, 256, 0, stream>>>(x, route, pmaxArr, blockOffsets, Xs);
    // 4: H = relu(Xs @ W1[e] + b1[e]) (bf16) WITH W2-transpose hidden in extra blocks
    gemm1_fused<<<dim3(MAXTILES + TRW2_XBLK, FFDIM / 128, 1), 256, 0, stream>>>(
        Xs, W1T, b1, H, segPrefix, tilePrefix, W2, W2T);
    // 5: out = H @ W2[e] + b2[e] (fp32)
    gemm_seg<false, float, FFDIM, DDIM><<<dim3(MAXTILES, DDIM / 128, 1), 256, 0, stream>>>(
        H, W2T, b2, out, segPrefix, tilePrefix);
}